// Round 4
// baseline (6888.794 us; speedup 1.0000x reference)
//
#include <hip/hip_runtime.h>
#include <hip/hip_bf16.h>

#define TOT85 1722695ULL  // 85 * 20267

using short8 = __attribute__((ext_vector_type(8))) short;
using f32x4  = __attribute__((ext_vector_type(4))) float;

__device__ __forceinline__ float bfbits2f(short u) {
  return __uint_as_float(((unsigned int)(unsigned short)u) << 16);
}
__device__ __forceinline__ short f2bfbits(float f) {
  __hip_bfloat16 h = __float2bfloat16(f);
  return *reinterpret_cast<short*>(&h);
}
__device__ __forceinline__ void gload_lds16(const void* g, void* l) {
  __builtin_amdgcn_global_load_lds(
      (const __attribute__((address_space(1))) unsigned int*)g,
      (__attribute__((address_space(3))) unsigned int*)l, 16, 0, 0);
}

// old-layout repack: [O][256][3][3] f32 -> [tap*8+chunk][NOCP oc][32 ic] bf16
// (consumed straight from global/L2 by the register-path kernel)
__global__ __launch_bounds__(256) void repack_k(const float* __restrict__ src,
                                                __hip_bfloat16* __restrict__ dst,
                                                int O, int NOCP, int ocoff) {
  int idx = blockIdx.x * 256 + threadIdx.x;
  if (idx >= O * 2304) return;
  int o = idx / 2304;
  int r = idx - o * 2304;
  int i = r / 9;       // ic 0..255
  int t = r - i * 9;   // tap 0..8
  dst[((size_t)(t * 8 + (i >> 5)) * NOCP + (o + ocoff)) * 32 + (i & 31)] =
      __float2bfloat16(src[idx]);
}

// big-layout repack: [256][256][3][3] f32 -> [ochalf 2][chunk 8][tap 9][128 oc][40] bf16
// pad bytes (ic 32..39) are never read as weights; chunk panel is glds-linear.
__global__ __launch_bounds__(256) void repack_big_k(const float* __restrict__ src,
                                                    __hip_bfloat16* __restrict__ dst) {
  int idx = blockIdx.x * 256 + threadIdx.x;
  if (idx >= 256 * 2304) return;
  int o = idx / 2304;
  int r = idx - o * 2304;
  int i = r / 9;
  int t = r - i * 9;
  dst[((((size_t)(o >> 7) * 8 + (i >> 5)) * 9 + t) * 128 + (o & 127)) * 40 + (i & 31)] =
      __float2bfloat16(src[idx]);
}

__global__ void locations_k(float* __restrict__ out, int HW, int W, float s) {
  int i = blockIdx.x * 256 + threadIdx.x;
  if (i >= HW) return;
  int y = i / W, x = i - y * W;
  out[2 * i + 0] = x * s + 0.5f * s;
  out[2 * i + 1] = y * s + 0.5f * s;
}

// ---------------- register-weight kernel (r1 structure) ----------------
// Block: 256 thr = 4 waves (2M x 2N). Tile: 128 pixels (8 rows x 16 cols) x NOC ocs.
// Weights: direct global->VGPR, double-buffered one tap ahead. 2 barriers per chunk.
template <int NREP, bool NORM_IN, bool STATS, int OUT_MODE, bool SRC_NCHW>
__global__ __launch_bounds__(256, NREP == 8 ? 2 : 3) void conv_mfma_k(
    const void* __restrict__ srcv, const __hip_bfloat16* __restrict__ wpk,
    const float* __restrict__ bias, const float* __restrict__ bias2,
    const float* __restrict__ statsIn, const float* __restrict__ gamma,
    const float* __restrict__ beta, float inv_cnt,
    __hip_bfloat16* __restrict__ dst, float* __restrict__ out,
    float* __restrict__ statsOut, const float* __restrict__ scales, int lvl,
    int H, int W, int oc_valid, int nTx, int NOCP) {
  constexpr int NOC = NREP * 32;
  __shared__ __align__(16) short s_in[180 * 40];
  __shared__ float s_red[64];
  __shared__ float s_a[256], s_c[256];

  const int tid = threadIdx.x;
  const int lane = tid & 63;
  const int wave = tid >> 6;
  const int wm = wave >> 1;
  const int wn = wave & 1;
  const int tIdx = blockIdx.x;
  const int ty = tIdx / nTx, tx = tIdx - ty * nTx;
  const int x0 = tx * 16, y0 = ty * 8;
  const int b = blockIdx.z;
  const int ocbase = blockIdx.y * NOC;
  const int HW = H * W;
  const int l15 = lane & 15;
  const int kg = lane >> 4;
  const int q8 = (tid & 3) * 8;

  if (STATS && tid < 64) s_red[tid] = 0.f;
  if (NORM_IN) {
    int g = tid >> 3;
    float s = statsIn[(b * 32 + g) * 2 + 0];
    float ss = statsIn[(b * 32 + g) * 2 + 1];
    float m = s * inv_cnt;
    float var = fmaf(-m, m, ss * inv_cnt);
    float rs = rsqrtf(var + 1e-5f);
    float avv = rs * gamma[tid];
    s_a[tid] = avv;
    s_c[tid] = fmaf(-m, avv, beta[tid]);
  }

  f32x4 acc[4][NREP];
#pragma unroll
  for (int m = 0; m < 4; ++m)
#pragma unroll
    for (int n = 0; n < NREP; ++n) acc[m][n] = (f32x4){0.f, 0.f, 0.f, 0.f};

  const short* wlane =
      (const short*)wpk + ((ocbase + wn * NREP * 16 + l15) * 32 + kg * 8);
  const size_t TAPSTR = (size_t)8 * NOCP * 32;

  for (int chunk = 0; chunk < 8; ++chunk) {
    const int ic0 = chunk * 32;
    __syncthreads();
    if (SRC_NCHW) {
      const float* srcf = (const float*)srcv;
      const int pix = tid;
      if (pix < 180) {
        int prow = pix / 18;
        int pcol = pix - prow * 18;
        int gy = y0 + prow - 1, gx = x0 + pcol - 1;
        short8 sv[4];
        bool valid = (gy >= 0 && gy < H && gx >= 0 && gx < W);
        if (valid) {
          const float* p = srcf + (((size_t)(b * 256 + ic0)) * H + gy) * W + gx;
#pragma unroll
          for (int q = 0; q < 4; ++q)
#pragma unroll
            for (int j = 0; j < 8; ++j)
              sv[q][j] = f2bfbits(p[(size_t)(q * 8 + j) * HW]);
        } else {
#pragma unroll
          for (int q = 0; q < 4; ++q) sv[q] = (short8)0;
        }
#pragma unroll
        for (int q = 0; q < 4; ++q) *(short8*)(s_in + pix * 40 + q * 8) = sv[q];
      }
    } else {
      const __hip_bfloat16* srcb = (const __hip_bfloat16*)srcv;
      float av[8], cv[8];
#pragma unroll
      for (int j = 0; j < 8; ++j) {
        int c2 = ic0 + q8 + j;
        av[j] = s_a[c2];
        cv[j] = s_c[c2];
      }
      for (int idx = tid; idx < 720; idx += 256) {
        int pix = idx >> 2;
        int prow = pix / 18;
        int pcol = pix - prow * 18;
        int gy = y0 + prow - 1, gx = x0 + pcol - 1;
        short8 o8 = (short8)0;
        if (gy >= 0 && gy < H && gx >= 0 && gx < W) {
          const short* sp =
              (const short*)srcb + ((((size_t)b * H + gy) * W + gx) * 256 + ic0 + q8);
          short8 v8 = *(const short8*)sp;
#pragma unroll
          for (int j = 0; j < 8; ++j)
            o8[j] = f2bfbits(fmaxf(fmaf(bfbits2f(v8[j]), av[j], cv[j]), 0.f));
        }
        *(short8*)(s_in + pix * 40 + q8) = o8;
      }
    }
    __syncthreads();

    const short* wch = wlane + (size_t)chunk * NOCP * 32;
    short8 bwA[NREP], bwB[NREP];
#pragma unroll
    for (int n = 0; n < NREP; ++n) bwA[n] = *(const short8*)(wch + n * 512);

    auto tapbody = [&](int tap, short8* curw, short8* nxtw) {
      if (tap < 8) {
        const short* wt = wch + (size_t)(tap + 1) * TAPSTR;
#pragma unroll
        for (int n = 0; n < NREP; ++n) nxtw[n] = *(const short8*)(wt + n * 512);
      }
      const int dy = tap / 3, dx = tap - dy * 3;
      short8 af[4];
#pragma unroll
      for (int m = 0; m < 4; ++m)
        af[m] = *(const short8*)(s_in + ((wm * 4 + m + dy) * 18 + (l15 + dx)) * 40 + kg * 8);
#pragma unroll
      for (int m = 0; m < 4; ++m)
#pragma unroll
        for (int n = 0; n < NREP; ++n)
          acc[m][n] = __builtin_amdgcn_mfma_f32_16x16x32_bf16(af[m], curw[n], acc[m][n], 0, 0, 0);
    };
#pragma unroll
    for (int tap = 0; tap < 9; tap += 2) {
      tapbody(tap, bwA, bwB);
      if (tap + 1 < 9) tapbody(tap + 1, bwB, bwA);
    }
  }

  const int masks[5] = {1, 2, 4, 16, 32};
#pragma unroll
  for (int n = 0; n < NREP; ++n) {
    int oc_l = wn * NREP * 16 + n * 16 + l15;
    int oc_g = ocbase + oc_l;
    float bv;
    if (OUT_MODE == 1)
      bv = (oc_g < 80) ? bias[oc_g] : ((oc_g == 80) ? bias2[0] : 0.f);
    else
      bv = (oc_g < oc_valid) ? bias[oc_g] : 0.f;
    float lsum = 0.f, lssq = 0.f;
#pragma unroll
    for (int m = 0; m < 4; ++m) {
      int oy = y0 + wm * 4 + m;
#pragma unroll
      for (int r = 0; r < 4; ++r) {
        int ox = x0 + kg * 4 + r;
        bool valid = (oy < H) && (ox < W) && (oc_g < oc_valid);
        float v = acc[m][n][r] + bv;
        if (valid) {
          if (OUT_MODE == 0) {
            dst[(((size_t)b * H + oy) * W + ox) * 256 + oc_g] = __float2bfloat16(v);
          } else if (OUT_MODE == 1) {
            int och = (oc_g == 80) ? 84 : oc_g;
            out[(size_t)b * TOT85 + (size_t)och * HW + oy * W + ox] = v;
          } else {
            out[(size_t)b * TOT85 + (size_t)(80 + oc_g) * HW + oy * W + ox] =
                expf(scales[lvl] * v);
          }
          if (STATS) {
            lsum += v;
            lssq += v * v;
          }
        }
      }
    }
    if (STATS) {
#pragma unroll
      for (int s = 0; s < 5; ++s) {
        lsum += __shfl_xor(lsum, masks[s], 64);
        lssq += __shfl_xor(lssq, masks[s], 64);
      }
      if ((lane & 55) == 0) {
        int g2 = ((wn * NREP + n) * 2 + ((lane >> 3) & 1)) * 2;
        atomicAdd(&s_red[g2 + 0], lsum);
        atomicAdd(&s_red[g2 + 1], lssq);
      }
    }
  }
  if (STATS) {
    __syncthreads();
    if (tid < NREP * 8)
      atomicAdd(&statsOut[(size_t)b * 64 + (ocbase >> 2) + tid], s_red[tid]);
  }
}

// ---------------- LDS-weight kernel (levels 0-1 towers) ----------------
// Block: 512 thr = 8 waves = 4 row-groups x 2 col-groups. Tile: 16 rows x 32 cols
// = 512 pixels x 128 ocs (blockIdx.y = oc half). Per wave: 64 pix x 128 oc,
// acc[4][8] (r1's proven MFMA:LDS-read shape).
// Per chunk: one global_load_lds burst stages the full 9-tap x 128-oc weight panel
// (92 KB) into LDS — shared by all 8 waves (3x less weight traffic than register
// path) — overlapped with input staging; then 9 barrier-free taps. 2 barriers/chunk.
// LDS 143 KB -> 1 block/CU, 2 waves/SIMD.
template <bool NORM_IN, bool SRC_NCHW>
__global__ __launch_bounds__(512, 2) void conv_big_k(
    const void* __restrict__ srcv, const __hip_bfloat16* __restrict__ wpk,
    const float* __restrict__ bias, const float* __restrict__ statsIn,
    const float* __restrict__ gamma, const float* __restrict__ beta, float inv_cnt,
    __hip_bfloat16* __restrict__ dst, float* __restrict__ statsOut,
    int H, int W, int nTx) {
  __shared__ __align__(16) short s_in[18 * 34 * 40];  // 48,960 B
  __shared__ __align__(16) short s_w[9 * 128 * 40];   // 92,160 B
  __shared__ float s_red[64];
  __shared__ float s_a[256], s_c[256];

  const int tid = threadIdx.x;
  const int lane = tid & 63;
  const int wave = tid >> 6;  // 0..7
  const int wr = wave >> 1;   // 0..3 row-group
  const int wc = wave & 1;    // 0..1 col-group
  const int tIdx = blockIdx.x;
  const int ty = tIdx / nTx, tx = tIdx - ty * nTx;
  const int x0 = tx * 32, y0 = ty * 16;
  const int b = blockIdx.z;
  const int ocbase = blockIdx.y * 128;
  const int HW = H * W;
  const int l15 = lane & 15;
  const int kg = lane >> 4;
  const int q8 = (tid & 3) * 8;

  if (tid < 64) s_red[tid] = 0.f;
  if (NORM_IN && tid < 256) {
    int g = tid >> 3;
    float s = statsIn[(b * 32 + g) * 2 + 0];
    float ss = statsIn[(b * 32 + g) * 2 + 1];
    float m = s * inv_cnt;
    float var = fmaf(-m, m, ss * inv_cnt);
    float rs = rsqrtf(var + 1e-5f);
    float avv = rs * gamma[tid];
    s_a[tid] = avv;
    s_c[tid] = fmaf(-m, avv, beta[tid]);
  }

  f32x4 acc[4][8];
#pragma unroll
  for (int m = 0; m < 4; ++m)
#pragma unroll
    for (int n = 0; n < 8; ++n) acc[m][n] = (f32x4){0.f, 0.f, 0.f, 0.f};

  // weight base for this oc-half: [chunk 8][tap 9][128][40] shorts
  const short* wbase = (const short*)wpk + (size_t)blockIdx.y * (8 * 9 * 128 * 40);

  for (int c = 0; c < 8; ++c) {
    const int ic0 = c * 32;
    __syncthreads();  // all reads of s_in/s_w from previous chunk complete
    // ---- weight panel: global -> LDS (zero VGPR), 5760 lane-loads of 16B ----
    {
      const short* wsrc = wbase + (size_t)c * (9 * 128 * 40);
#pragma unroll
      for (int r = 0; r < 12; ++r) {
        int u = r * 512 + tid;
        if (u < 5760)  // wave-uniform guard (5760 = 90 waves * 64)
          gload_lds16(wsrc + (size_t)u * 8, s_w + (size_t)(r * 512 + wave * 64) * 8);
      }
    }
    // ---- input staging (global latency overlaps the glds burst) ----
    if (SRC_NCHW) {
      const float* srcf = (const float*)srcv;
#pragma unroll
      for (int r = 0; r < 2; ++r) {
        int pix = r * 512 + tid;
        if (pix < 612) {  // 18 rows x 34 cols
          int prow = pix / 34;
          int pcol = pix - prow * 34;
          int gy = y0 + prow - 1, gx = x0 + pcol - 1;
          short8 sv[4];
          bool valid = (gy >= 0 && gy < H && gx >= 0 && gx < W);
          if (valid) {
            const float* p = srcf + (((size_t)(b * 256 + ic0)) * H + gy) * W + gx;
#pragma unroll
            for (int q = 0; q < 4; ++q)
#pragma unroll
              for (int j = 0; j < 8; ++j)
                sv[q][j] = f2bfbits(p[(size_t)(q * 8 + j) * HW]);
          } else {
#pragma unroll
            for (int q = 0; q < 4; ++q) sv[q] = (short8)0;
          }
#pragma unroll
          for (int q = 0; q < 4; ++q) *(short8*)(s_in + (size_t)pix * 40 + q * 8) = sv[q];
        }
      }
    } else {
      const __hip_bfloat16* srcb = (const __hip_bfloat16*)srcv;
      float av[8], cv[8];
#pragma unroll
      for (int j = 0; j < 8; ++j) {
        int c2 = ic0 + q8 + j;
        av[j] = s_a[c2];
        cv[j] = s_c[c2];
      }
#pragma unroll
      for (int r = 0; r < 5; ++r) {
        int u = r * 512 + tid;
        if (u < 2448) {  // 612 pix x 4 quads; u&3 == tid&3 (512%4==0)
          int pix = u >> 2;
          int prow = pix / 34;
          int pcol = pix - prow * 34;
          int gy = y0 + prow - 1, gx = x0 + pcol - 1;
          short8 o8 = (short8)0;
          if (gy >= 0 && gy < H && gx >= 0 && gx < W) {
            const short* sp =
                (const short*)srcb + ((((size_t)b * H + gy) * W + gx) * 256 + ic0 + q8);
            short8 v8 = *(const short8*)sp;
#pragma unroll
            for (int j = 0; j < 8; ++j)
              o8[j] = f2bfbits(fmaxf(fmaf(bfbits2f(v8[j]), av[j], cv[j]), 0.f));
          }
          *(short8*)(s_in + (size_t)pix * 40 + q8) = o8;
        }
      }
    }
    __syncthreads();  // drains vmcnt(0): glds + staging loads; lgkm: ds_writes

    // ---- 9 taps, barrier-free ----
#pragma unroll
    for (int tap = 0; tap < 9; ++tap) {
      const int dy = tap / 3, dx = tap - dy * 3;
      short8 af[4];
#pragma unroll
      for (int m = 0; m < 4; ++m)
        af[m] = *(const short8*)(s_in +
                                 ((size_t)((wr * 4 + m + dy) * 34 + (wc * 16 + l15 + dx))) * 40 +
                                 kg * 8);
      short8 wf[8];
#pragma unroll
      for (int n = 0; n < 8; ++n)
        wf[n] = *(const short8*)(s_w + ((size_t)(tap * 128 + n * 16 + l15)) * 40 + kg * 8);
#pragma unroll
      for (int m = 0; m < 4; ++m)
#pragma unroll
        for (int n = 0; n < 8; ++n)
          acc[m][n] = __builtin_amdgcn_mfma_f32_16x16x32_bf16(af[m], wf[n], acc[m][n], 0, 0, 0);
    }
  }

  // ---- epilogue: bias, NHWC store, GN stats ----
  const int masks[5] = {1, 2, 4, 16, 32};
#pragma unroll
  for (int n = 0; n < 8; ++n) {
    int oc_g = ocbase + n * 16 + l15;
    float bv = bias[oc_g];
    float lsum = 0.f, lssq = 0.f;
#pragma unroll
    for (int m = 0; m < 4; ++m) {
      int oy = y0 + wr * 4 + m;
#pragma unroll
      for (int r = 0; r < 4; ++r) {
        int ox = x0 + wc * 16 + kg * 4 + r;
        bool valid = (oy < H) && (ox < W);
        float v = acc[m][n][r] + bv;
        if (valid) {
          dst[(((size_t)b * H + oy) * W + ox) * 256 + oc_g] = __float2bfloat16(v);
          lsum += v;
          lssq += v * v;
        }
      }
    }
#pragma unroll
    for (int s = 0; s < 5; ++s) {
      lsum += __shfl_xor(lsum, masks[s], 64);
      lssq += __shfl_xor(lssq, masks[s], 64);
    }
    if ((lane & 55) == 0) {  // lanes 0 and 8
      int g2 = (n * 2 + ((lane >> 3) & 1)) * 2;
      atomicAdd(&s_red[g2 + 0], lsum);
      atomicAdd(&s_red[g2 + 1], lssq);
    }
  }
  __syncthreads();
  if (tid < 32) atomicAdd(&statsOut[(size_t)b * 64 + (ocbase >> 2) + tid], s_red[tid]);
}

extern "C" void kernel_launch(void* const* d_in, const int* in_sizes, int n_in,
                              void* d_out_v, int out_size, void* d_ws, size_t ws_size,
                              hipStream_t stream) {
  (void)in_sizes; (void)n_in; (void)out_size; (void)ws_size;
  static const int HS[5] = {100, 50, 25, 13, 7};
  static const int WSd[5] = {152, 76, 38, 19, 10};
  static const int STRD[5] = {8, 16, 32, 64, 128};

  const float* feat[5];
  for (int i = 0; i < 5; ++i) feat[i] = (const float*)d_in[i];
  const float* cls_w = (const float*)d_in[5];
  const float* cls_b = (const float*)d_in[6];
  const float* cls_g = (const float*)d_in[7];
  const float* cls_bb = (const float*)d_in[8];
  const float* box_w = (const float*)d_in[9];
  const float* box_b = (const float*)d_in[10];
  const float* box_g = (const float*)d_in[11];
  const float* box_bb = (const float*)d_in[12];
  const float* logits_w = (const float*)d_in[13];
  const float* logits_b = (const float*)d_in[14];
  const float* ctr_w = (const float*)d_in[15];
  const float* ctr_b = (const float*)d_in[16];
  const float* reg_w = (const float*)d_in[17];
  const float* reg_b = (const float*)d_in[18];
  const float* scales = (const float*)d_in[19];
  float* d_out = (float*)d_out_v;

  char* wsp = (char*)d_ws;
  size_t off = 0;
  auto carve = [&](size_t bytes) -> char* {
    char* p = wsp + off;
    off += (bytes + 255) & ~(size_t)255;
    return p;
  };
  const size_t MAXE = (size_t)8 * 100 * 152 * 256;
  __hip_bfloat16* bufA = (__hip_bfloat16*)carve(MAXE * 2);
  __hip_bfloat16* bufB = (__hip_bfloat16*)carve(MAXE * 2);
  const size_t TW = (size_t)9 * 8 * 256 * 32;       // old layout, per conv
  const size_t TWB = (size_t)2 * 8 * 9 * 128 * 40;  // big layout, per conv
  __hip_bfloat16* wpk_cls = (__hip_bfloat16*)carve(4 * TW * 2);
  __hip_bfloat16* wpk_box = (__hip_bfloat16*)carve(4 * TW * 2);
  __hip_bfloat16* big_cls = (__hip_bfloat16*)carve(4 * TWB * 2);
  __hip_bfloat16* big_box = (__hip_bfloat16*)carve(4 * TWB * 2);
  __hip_bfloat16* wpk_clsh = (__hip_bfloat16*)carve((size_t)9 * 8 * 96 * 32 * 2);
  __hip_bfloat16* wpk_regh = (__hip_bfloat16*)carve((size_t)9 * 8 * 32 * 32 * 2);
  float* stats_all = (float*)carve((size_t)40 * 8 * 64 * 4);

  hipMemsetAsync(stats_all, 0, (size_t)40 * 8 * 64 * 4, stream);

  auto rp = [&](const float* s, __hip_bfloat16* d, int O, int NOCP, int ocoff) {
    int total = O * 2304;
    hipLaunchKernelGGL(repack_k, dim3((total + 255) / 256), dim3(256), 0, stream, s, d, O, NOCP,
                       ocoff);
  };
  for (int i = 0; i < 4; ++i) {
    rp(cls_w + (size_t)i * 256 * 2304, wpk_cls + (size_t)i * TW, 256, 256, 0);
    rp(box_w + (size_t)i * 256 * 2304, wpk_box + (size_t)i * TW, 256, 256, 0);
    hipLaunchKernelGGL(repack_big_k, dim3(2304), dim3(256), 0, stream,
                       cls_w + (size_t)i * 256 * 2304, big_cls + (size_t)i * TWB);
    hipLaunchKernelGGL(repack_big_k, dim3(2304), dim3(256), 0, stream,
                       box_w + (size_t)i * 256 * 2304, big_box + (size_t)i * TWB);
  }
  rp(logits_w, wpk_clsh, 80, 96, 0);
  rp(ctr_w, wpk_clsh, 1, 96, 80);
  rp(reg_w, wpk_regh, 4, 32, 0);

  size_t out_lvl_off = 0, loc_off = 0;
  const size_t OUT0 = (size_t)8 * TOT85;

  for (int l = 0; l < 5; ++l) {
    int H = HS[l], W = WSd[l], HW = H * W;
    int nTxS = (W + 15) / 16, nTyS = (H + 7) / 8;    // 8x16 tiling (old kernel)
    int nTxB = (W + 31) / 32, nTyB = (H + 15) / 16;  // 16x32 tiling (big kernel)
    dim3 gridS(nTxS * nTyS, 1, 8);
    dim3 gridB(nTxB * nTyB, 2, 8);
    dim3 blk(256), blkB(512);
    float inv_cnt = 1.f / (8.f * (float)HW);
    float* out_lvl = d_out + out_lvl_off;

    hipLaunchKernelGGL(locations_k, dim3((HW + 255) / 256), blk, 0, stream,
                       d_out + OUT0 + 2 * loc_off, HW, W, (float)STRD[l]);

    for (int t = 0; t < 2; ++t) {
      const __hip_bfloat16* wpkT = (t == 0) ? wpk_cls : wpk_box;
      const __hip_bfloat16* bigT = (t == 0) ? big_cls : big_box;
      const float* bt = (t == 0) ? cls_b : box_b;
      const float* gt = (t == 0) ? cls_g : box_g;
      const float* bbt = (t == 0) ? cls_bb : box_bb;
      float* slot = stats_all + (size_t)(l * 2 + t) * 4 * 512;

      __hip_bfloat16* cur;
      __hip_bfloat16* nxt;
      if (l <= 1) {
        // LDS-weight path
        hipLaunchKernelGGL((conv_big_k<false, true>), gridB, blkB, 0, stream,
                           (const void*)feat[l], bigT, bt, (const float*)nullptr,
                           (const float*)nullptr, (const float*)nullptr, 0.f, bufA, slot, H, W,
                           nTxB);
        cur = bufA;
        nxt = bufB;
        for (int i = 1; i < 4; ++i) {
          hipLaunchKernelGGL((conv_big_k<true, false>), gridB, blkB, 0, stream,
                             (const void*)cur, bigT + (size_t)i * TWB, bt + i * 256,
                             slot + (size_t)(i - 1) * 512, gt + (i - 1) * 256,
                             bbt + (i - 1) * 256, inv_cnt, nxt, slot + (size_t)i * 512, H, W,
                             nTxB);
          __hip_bfloat16* tmp = cur;
          cur = nxt;
          nxt = tmp;
        }
      } else {
        // register-weight path (r1 config: NREP=8, no oc split)
        hipLaunchKernelGGL((conv_mfma_k<8, false, true, 0, true>), gridS, blk, 0, stream,
                           (const void*)feat[l], wpkT, bt, (const float*)nullptr,
                           (const float*)nullptr, (const float*)nullptr, (const float*)nullptr,
                           0.f, bufA, (float*)nullptr, slot, scales, l, H, W, 256, nTxS, 256);
        cur = bufA;
        nxt = bufB;
        for (int i = 1; i < 4; ++i) {
          hipLaunchKernelGGL((conv_mfma_k<8, true, true, 0, false>), gridS, blk, 0, stream,
                             (const void*)cur, wpkT + (size_t)i * TW, bt + i * 256,
                             (const float*)nullptr, slot + (size_t)(i - 1) * 512,
                             gt + (i - 1) * 256, bbt + (i - 1) * 256, inv_cnt, nxt,
                             (float*)nullptr, slot + (size_t)i * 512, scales, l, H, W, 256,
                             nTxS, 256);
          __hip_bfloat16* tmp = cur;
          cur = nxt;
          nxt = tmp;
        }
      }
      if (t == 0) {
        hipLaunchKernelGGL((conv_mfma_k<3, true, false, 1, false>), gridS, blk, 0, stream,
                           (const void*)cur, wpk_clsh, logits_b, ctr_b,
                           slot + (size_t)3 * 512, gt + 3 * 256, bbt + 3 * 256, inv_cnt,
                           (__hip_bfloat16*)nullptr, out_lvl, (float*)nullptr, scales, l, H, W,
                           81, nTxS, 96);
      } else {
        hipLaunchKernelGGL((conv_mfma_k<1, true, false, 2, false>), gridS, blk, 0, stream,
                           (const void*)cur, wpk_regh, reg_b, (const float*)nullptr,
                           slot + (size_t)3 * 512, gt + 3 * 256, bbt + 3 * 256, inv_cnt,
                           (__hip_bfloat16*)nullptr, out_lvl, (float*)nullptr, scales, l, H, W,
                           4, nTxS, 32);
      }
    }
    out_lvl_off += (size_t)85 * HW;
    loc_off += HW;
  }
}

// Round 5
// 4943.015 us; speedup vs baseline: 1.3936x; 1.3936x over previous
//
#include <hip/hip_runtime.h>
#include <hip/hip_bf16.h>

#define TOT85 1722695ULL  // 85 * 20267

using short8 = __attribute__((ext_vector_type(8))) short;
using f32x4  = __attribute__((ext_vector_type(4))) float;

__device__ __forceinline__ float bfbits2f(short u) {
  return __uint_as_float(((unsigned int)(unsigned short)u) << 16);
}
__device__ __forceinline__ short f2bfbits(float f) {
  __hip_bfloat16 h = __float2bfloat16(f);
  return *reinterpret_cast<short*>(&h);
}

// repack conv weight [O][256][3][3] f32 -> [tap*8+chunk][NOCP oc][32 ic] bf16
// (weights consumed straight from global/L2; stride-32 rows = coalesced 1KB fragments)
__global__ __launch_bounds__(256) void repack_k(const float* __restrict__ src,
                                                __hip_bfloat16* __restrict__ dst,
                                                int O, int NOCP, int ocoff) {
  int idx = blockIdx.x * 256 + threadIdx.x;
  if (idx >= O * 2304) return;
  int o = idx / 2304;
  int r = idx - o * 2304;
  int i = r / 9;       // ic 0..255
  int t = r - i * 9;   // tap 0..8
  dst[((size_t)(t * 8 + (i >> 5)) * NOCP + (o + ocoff)) * 32 + (i & 31)] =
      __float2bfloat16(src[idx]);
}

__global__ void locations_k(float* __restrict__ out, int HW, int W, float s) {
  int i = blockIdx.x * 256 + threadIdx.x;
  if (i >= HW) return;
  int y = i / W, x = i - y * W;
  out[2 * i + 0] = x * s + 0.5f * s;
  out[2 * i + 1] = y * s + 0.5f * s;
}

// ---------------- tower kernel: 1M x 4N wave layout ----------------
// Block: 256 thr = 4 waves. Tile: 128 pixels (8 rows x 16 cols) x 256 ocs.
// Each wave owns a 64-oc slice (wave*64) and ALL 128 pixels: acc[8][4].
// Weight VMEM issue per CU-K-step halves vs 2Mx2N (no wm duplication);
// A-fragments come from LDS (parallel pipe). 2 barriers per chunk, tap loop
// barrier-free with 1-tap register double-buffer of weights (r1 structure).
template <bool NORM_IN, bool SRC_NCHW>
__global__ __launch_bounds__(256, 2) void conv_tower_k(
    const void* __restrict__ srcv, const __hip_bfloat16* __restrict__ wpk,
    const float* __restrict__ bias, const float* __restrict__ statsIn,
    const float* __restrict__ gamma, const float* __restrict__ beta, float inv_cnt,
    __hip_bfloat16* __restrict__ dst, float* __restrict__ statsOut,
    int H, int W, int nTx) {
  __shared__ __align__(16) short s_in[180 * 40];
  __shared__ float s_red[64];
  __shared__ float s_a[256], s_c[256];

  const int tid = threadIdx.x;
  const int lane = tid & 63;
  const int wave = tid >> 6;  // 0..3 = oc-slice
  const int tIdx = blockIdx.x;
  const int ty = tIdx / nTx, tx = tIdx - ty * nTx;
  const int x0 = tx * 16, y0 = ty * 8;
  const int b = blockIdx.z;
  const int HW = H * W;
  const int l15 = lane & 15;
  const int kg = lane >> 4;  // 0..3
  const int q8 = (tid & 3) * 8;

  if (tid < 64) s_red[tid] = 0.f;
  if (NORM_IN) {
    int g = tid >> 3;
    float s = statsIn[(b * 32 + g) * 2 + 0];
    float ss = statsIn[(b * 32 + g) * 2 + 1];
    float m = s * inv_cnt;
    float var = fmaf(-m, m, ss * inv_cnt);
    float rs = rsqrtf(var + 1e-5f);
    float avv = rs * gamma[tid];
    s_a[tid] = avv;
    s_c[tid] = fmaf(-m, avv, beta[tid]);
  }

  f32x4 acc[8][4];
#pragma unroll
  for (int m = 0; m < 8; ++m)
#pragma unroll
    for (int n = 0; n < 4; ++n) acc[m][n] = (f32x4){0.f, 0.f, 0.f, 0.f};

  // per-lane weight pointer: elem = ((tap*8+chunk)*256 + wave*64 + n*16 + l15)*32 + kg*8
  const short* wlane = (const short*)wpk + ((wave * 64 + l15) * 32 + kg * 8);
  const size_t TAPSTR = (size_t)8 * 256 * 32;

  for (int chunk = 0; chunk < 8; ++chunk) {
    const int ic0 = chunk * 32;
    __syncthreads();  // protect s_in from previous chunk's readers (orders s_a/s_c too)
    if (SRC_NCHW) {
      const float* srcf = (const float*)srcv;
      const int pix = tid;
      if (pix < 180) {
        int prow = pix / 18;
        int pcol = pix - prow * 18;
        int gy = y0 + prow - 1, gx = x0 + pcol - 1;
        short8 sv[4];
        bool valid = (gy >= 0 && gy < H && gx >= 0 && gx < W);
        if (valid) {
          const float* p = srcf + (((size_t)(b * 256 + ic0)) * H + gy) * W + gx;
#pragma unroll
          for (int q = 0; q < 4; ++q)
#pragma unroll
            for (int j = 0; j < 8; ++j)
              sv[q][j] = f2bfbits(p[(size_t)(q * 8 + j) * HW]);
        } else {
#pragma unroll
          for (int q = 0; q < 4; ++q) sv[q] = (short8)0;
        }
#pragma unroll
        for (int q = 0; q < 4; ++q) *(short8*)(s_in + pix * 40 + q * 8) = sv[q];
      }
    } else {
      const __hip_bfloat16* srcb = (const __hip_bfloat16*)srcv;
      float av[8], cv[8];
#pragma unroll
      for (int j = 0; j < 8; ++j) {
        int c2 = ic0 + q8 + j;
        av[j] = s_a[c2];
        cv[j] = s_c[c2];
      }
      for (int idx = tid; idx < 720; idx += 256) {  // 180 pix x 4 quads(8ic)
        int pix = idx >> 2;
        int prow = pix / 18;
        int pcol = pix - prow * 18;
        int gy = y0 + prow - 1, gx = x0 + pcol - 1;
        short8 o8 = (short8)0;
        if (gy >= 0 && gy < H && gx >= 0 && gx < W) {
          const short* sp =
              (const short*)srcb + ((((size_t)b * H + gy) * W + gx) * 256 + ic0 + q8);
          short8 v8 = *(const short8*)sp;
#pragma unroll
          for (int j = 0; j < 8; ++j)
            o8[j] = f2bfbits(fmaxf(fmaf(bfbits2f(v8[j]), av[j], cv[j]), 0.f));
        }
        *(short8*)(s_in + pix * 40 + q8) = o8;
      }
    }
    __syncthreads();

    const short* wch = wlane + (size_t)chunk * 256 * 32;
    short8 bwA[4], bwB[4];
#pragma unroll
    for (int n = 0; n < 4; ++n) bwA[n] = *(const short8*)(wch + n * 512);

    auto tapbody = [&](int tap, short8* curw, short8* nxtw) {
      if (tap < 8) {  // prefetch next tap's weights (L1/L2-resident)
        const short* wt = wch + (size_t)(tap + 1) * TAPSTR;
#pragma unroll
        for (int n = 0; n < 4; ++n) nxtw[n] = *(const short8*)(wt + n * 512);
      }
      const int dy = tap / 3, dx = tap - dy * 3;
      short8 af[8];
#pragma unroll
      for (int m = 0; m < 8; ++m)
        af[m] = *(const short8*)(s_in + ((m + dy) * 18 + (l15 + dx)) * 40 + kg * 8);
#pragma unroll
      for (int m = 0; m < 8; ++m)
#pragma unroll
        for (int n = 0; n < 4; ++n)
          acc[m][n] = __builtin_amdgcn_mfma_f32_16x16x32_bf16(af[m], curw[n], acc[m][n], 0, 0, 0);
    };
#pragma unroll
    for (int tap = 0; tap < 9; tap += 2) {
      tapbody(tap, bwA, bwB);
      if (tap + 1 < 9) tapbody(tap + 1, bwB, bwA);
    }
  }

  // epilogue: bias, NHWC bf16 store, GN stats
  const int masks[5] = {1, 2, 4, 16, 32};
#pragma unroll
  for (int n = 0; n < 4; ++n) {
    int oc_g = wave * 64 + n * 16 + l15;
    float bv = bias[oc_g];
    float lsum = 0.f, lssq = 0.f;
#pragma unroll
    for (int m = 0; m < 8; ++m) {
      int oy = y0 + m;
#pragma unroll
      for (int r = 0; r < 4; ++r) {
        int ox = x0 + kg * 4 + r;
        bool valid = (oy < H) && (ox < W);
        float v = acc[m][n][r] + bv;
        if (valid) {
          dst[(((size_t)b * H + oy) * W + ox) * 256 + oc_g] = __float2bfloat16(v);
          lsum += v;
          lssq += v * v;
        }
      }
    }
#pragma unroll
    for (int s = 0; s < 5; ++s) {
      lsum += __shfl_xor(lsum, masks[s], 64);
      lssq += __shfl_xor(lssq, masks[s], 64);
    }
    if ((lane & 55) == 0) {  // lanes 0 and 8: two 8-oc GN sub-groups
      int g2 = (wave * 8 + n * 2 + ((lane >> 3) & 1)) * 2;
      atomicAdd(&s_red[g2 + 0], lsum);
      atomicAdd(&s_red[g2 + 1], lssq);
    }
  }
  __syncthreads();
  if (tid < 64) atomicAdd(&statsOut[(size_t)b * 64 + tid], s_red[tid]);
}

// ---------------- head kernel (r1/r3 proven register path, 2Mx2N) ----------------
// OUT_MODE: 1 = d_out fp32 (logits oc<80, ctr oc==80 -> ch84);
//           2 = d_out fp32 expf(scale*v) at ch 80+oc.
template <int NREP, int OUT_MODE>
__global__ __launch_bounds__(256, 3) void conv_head_k(
    const void* __restrict__ srcv, const __hip_bfloat16* __restrict__ wpk,
    const float* __restrict__ bias, const float* __restrict__ bias2,
    const float* __restrict__ statsIn, const float* __restrict__ gamma,
    const float* __restrict__ beta, float inv_cnt,
    float* __restrict__ out, const float* __restrict__ scales, int lvl,
    int H, int W, int oc_valid, int nTx, int NOCP) {
  __shared__ __align__(16) short s_in[180 * 40];
  __shared__ float s_a[256], s_c[256];

  const int tid = threadIdx.x;
  const int lane = tid & 63;
  const int wave = tid >> 6;
  const int wm = wave >> 1;
  const int wn = wave & 1;
  const int tIdx = blockIdx.x;
  const int ty = tIdx / nTx, tx = tIdx - ty * nTx;
  const int x0 = tx * 16, y0 = ty * 8;
  const int b = blockIdx.z;
  const int HW = H * W;
  const int l15 = lane & 15;
  const int kg = lane >> 4;
  const int q8 = (tid & 3) * 8;

  {
    int g = tid >> 3;
    float s = statsIn[(b * 32 + g) * 2 + 0];
    float ss = statsIn[(b * 32 + g) * 2 + 1];
    float m = s * inv_cnt;
    float var = fmaf(-m, m, ss * inv_cnt);
    float rs = rsqrtf(var + 1e-5f);
    float avv = rs * gamma[tid];
    s_a[tid] = avv;
    s_c[tid] = fmaf(-m, avv, beta[tid]);
  }

  f32x4 acc[4][NREP];
#pragma unroll
  for (int m = 0; m < 4; ++m)
#pragma unroll
    for (int n = 0; n < NREP; ++n) acc[m][n] = (f32x4){0.f, 0.f, 0.f, 0.f};

  const short* wlane = (const short*)wpk + ((wn * NREP * 16 + l15) * 32 + kg * 8);
  const size_t TAPSTR = (size_t)8 * NOCP * 32;

  for (int chunk = 0; chunk < 8; ++chunk) {
    const int ic0 = chunk * 32;
    __syncthreads();
    {
      const __hip_bfloat16* srcb = (const __hip_bfloat16*)srcv;
      float av[8], cv[8];
#pragma unroll
      for (int j = 0; j < 8; ++j) {
        int c2 = ic0 + q8 + j;
        av[j] = s_a[c2];
        cv[j] = s_c[c2];
      }
      for (int idx = tid; idx < 720; idx += 256) {
        int pix = idx >> 2;
        int prow = pix / 18;
        int pcol = pix - prow * 18;
        int gy = y0 + prow - 1, gx = x0 + pcol - 1;
        short8 o8 = (short8)0;
        if (gy >= 0 && gy < H && gx >= 0 && gx < W) {
          const short* sp =
              (const short*)srcb + ((((size_t)b * H + gy) * W + gx) * 256 + ic0 + q8);
          short8 v8 = *(const short8*)sp;
#pragma unroll
          for (int j = 0; j < 8; ++j)
            o8[j] = f2bfbits(fmaxf(fmaf(bfbits2f(v8[j]), av[j], cv[j]), 0.f));
        }
        *(short8*)(s_in + pix * 40 + q8) = o8;
      }
    }
    __syncthreads();

    const short* wch = wlane + (size_t)chunk * NOCP * 32;
    short8 bwA[NREP], bwB[NREP];
#pragma unroll
    for (int n = 0; n < NREP; ++n) bwA[n] = *(const short8*)(wch + n * 512);

    auto tapbody = [&](int tap, short8* curw, short8* nxtw) {
      if (tap < 8) {
        const short* wt = wch + (size_t)(tap + 1) * TAPSTR;
#pragma unroll
        for (int n = 0; n < NREP; ++n) nxtw[n] = *(const short8*)(wt + n * 512);
      }
      const int dy = tap / 3, dx = tap - dy * 3;
      short8 af[4];
#pragma unroll
      for (int m = 0; m < 4; ++m)
        af[m] = *(const short8*)(s_in + ((wm * 4 + m + dy) * 18 + (l15 + dx)) * 40 + kg * 8);
#pragma unroll
      for (int m = 0; m < 4; ++m)
#pragma unroll
        for (int n = 0; n < NREP; ++n)
          acc[m][n] = __builtin_amdgcn_mfma_f32_16x16x32_bf16(af[m], curw[n], acc[m][n], 0, 0, 0);
    };
#pragma unroll
    for (int tap = 0; tap < 9; tap += 2) {
      tapbody(tap, bwA, bwB);
      if (tap + 1 < 9) tapbody(tap + 1, bwB, bwA);
    }
  }

#pragma unroll
  for (int n = 0; n < NREP; ++n) {
    int oc_l = wn * NREP * 16 + n * 16 + l15;
    float bv;
    if (OUT_MODE == 1)
      bv = (oc_l < 80) ? bias[oc_l] : ((oc_l == 80) ? bias2[0] : 0.f);
    else
      bv = (oc_l < oc_valid) ? bias[oc_l] : 0.f;
#pragma unroll
    for (int m = 0; m < 4; ++m) {
      int oy = y0 + wm * 4 + m;
#pragma unroll
      for (int r = 0; r < 4; ++r) {
        int ox = x0 + kg * 4 + r;
        bool valid = (oy < H) && (ox < W) && (oc_l < oc_valid);
        float v = acc[m][n][r] + bv;
        if (valid) {
          if (OUT_MODE == 1) {
            int och = (oc_l == 80) ? 84 : oc_l;
            out[(size_t)b * TOT85 + (size_t)och * HW + oy * W + ox] = v;
          } else {
            out[(size_t)b * TOT85 + (size_t)(80 + oc_l) * HW + oy * W + ox] =
                expf(scales[lvl] * v);
          }
        }
      }
    }
  }
}

extern "C" void kernel_launch(void* const* d_in, const int* in_sizes, int n_in,
                              void* d_out_v, int out_size, void* d_ws, size_t ws_size,
                              hipStream_t stream) {
  (void)in_sizes; (void)n_in; (void)out_size; (void)ws_size;
  static const int HS[5] = {100, 50, 25, 13, 7};
  static const int WSd[5] = {152, 76, 38, 19, 10};
  static const int STRD[5] = {8, 16, 32, 64, 128};

  const float* feat[5];
  for (int i = 0; i < 5; ++i) feat[i] = (const float*)d_in[i];
  const float* cls_w = (const float*)d_in[5];
  const float* cls_b = (const float*)d_in[6];
  const float* cls_g = (const float*)d_in[7];
  const float* cls_bb = (const float*)d_in[8];
  const float* box_w = (const float*)d_in[9];
  const float* box_b = (const float*)d_in[10];
  const float* box_g = (const float*)d_in[11];
  const float* box_bb = (const float*)d_in[12];
  const float* logits_w = (const float*)d_in[13];
  const float* logits_b = (const float*)d_in[14];
  const float* ctr_w = (const float*)d_in[15];
  const float* ctr_b = (const float*)d_in[16];
  const float* reg_w = (const float*)d_in[17];
  const float* reg_b = (const float*)d_in[18];
  const float* scales = (const float*)d_in[19];
  float* d_out = (float*)d_out_v;

  char* wsp = (char*)d_ws;
  size_t off = 0;
  auto carve = [&](size_t bytes) -> char* {
    char* p = wsp + off;
    off += (bytes + 255) & ~(size_t)255;
    return p;
  };
  const size_t MAXE = (size_t)8 * 100 * 152 * 256;  // 31.13M elems
  __hip_bfloat16* bufA = (__hip_bfloat16*)carve(MAXE * 2);
  __hip_bfloat16* bufB = (__hip_bfloat16*)carve(MAXE * 2);
  const size_t TW = (size_t)9 * 8 * 256 * 32;  // per tower conv
  __hip_bfloat16* wpk_cls = (__hip_bfloat16*)carve(4 * TW * 2);
  __hip_bfloat16* wpk_box = (__hip_bfloat16*)carve(4 * TW * 2);
  __hip_bfloat16* wpk_clsh = (__hip_bfloat16*)carve((size_t)9 * 8 * 96 * 32 * 2);
  __hip_bfloat16* wpk_regh = (__hip_bfloat16*)carve((size_t)9 * 8 * 32 * 32 * 2);
  float* stats_all = (float*)carve((size_t)40 * 8 * 64 * 4);

  hipMemsetAsync(stats_all, 0, (size_t)40 * 8 * 64 * 4, stream);

  auto rp = [&](const float* s, __hip_bfloat16* d, int O, int NOCP, int ocoff) {
    int total = O * 2304;
    hipLaunchKernelGGL(repack_k, dim3((total + 255) / 256), dim3(256), 0, stream, s, d, O, NOCP,
                       ocoff);
  };
  for (int i = 0; i < 4; ++i) {
    rp(cls_w + (size_t)i * 256 * 2304, wpk_cls + (size_t)i * TW, 256, 256, 0);
    rp(box_w + (size_t)i * 256 * 2304, wpk_box + (size_t)i * TW, 256, 256, 0);
  }
  rp(logits_w, wpk_clsh, 80, 96, 0);
  rp(ctr_w, wpk_clsh, 1, 96, 80);
  rp(reg_w, wpk_regh, 4, 32, 0);

  size_t out_lvl_off = 0, loc_off = 0;
  const size_t OUT0 = (size_t)8 * TOT85;

  for (int l = 0; l < 5; ++l) {
    int H = HS[l], W = WSd[l], HW = H * W;
    int nTx = (W + 15) / 16, nTy = (H + 7) / 8;
    dim3 grid(nTx * nTy, 1, 8);
    dim3 blk(256);
    float inv_cnt = 1.f / (8.f * (float)HW);
    float* out_lvl = d_out + out_lvl_off;

    hipLaunchKernelGGL(locations_k, dim3((HW + 255) / 256), blk, 0, stream,
                       d_out + OUT0 + 2 * loc_off, HW, W, (float)STRD[l]);

    for (int t = 0; t < 2; ++t) {
      const __hip_bfloat16* wpkT = (t == 0) ? wpk_cls : wpk_box;
      const float* bt = (t == 0) ? cls_b : box_b;
      const float* gt = (t == 0) ? cls_g : box_g;
      const float* bbt = (t == 0) ? cls_bb : box_bb;
      float* slot = stats_all + (size_t)(l * 2 + t) * 4 * 512;  // 512 floats per conv slot

      // conv 0: NCHW f32 input, no norm, writes stats slot 0
      hipLaunchKernelGGL((conv_tower_k<false, true>), grid, blk, 0, stream,
                         (const void*)feat[l], wpkT, bt, (const float*)nullptr,
                         (const float*)nullptr, (const float*)nullptr, 0.f, bufA, slot, H, W,
                         nTx);
      __hip_bfloat16* cur = bufA;
      __hip_bfloat16* nxt = bufB;
      for (int i = 1; i < 4; ++i) {
        hipLaunchKernelGGL((conv_tower_k<true, false>), grid, blk, 0, stream,
                           (const void*)cur, wpkT + (size_t)i * TW, bt + i * 256,
                           slot + (size_t)(i - 1) * 512, gt + (i - 1) * 256,
                           bbt + (i - 1) * 256, inv_cnt, nxt, slot + (size_t)i * 512, H, W,
                           nTx);
        __hip_bfloat16* tmp = cur;
        cur = nxt;
        nxt = tmp;
      }
      if (t == 0) {
        hipLaunchKernelGGL((conv_head_k<3, 1>), grid, blk, 0, stream,
                           (const void*)cur, wpk_clsh, logits_b, ctr_b,
                           slot + (size_t)3 * 512, gt + 3 * 256, bbt + 3 * 256, inv_cnt,
                           out_lvl, scales, l, H, W, 81, nTx, 96);
      } else {
        hipLaunchKernelGGL((conv_head_k<1, 2>), grid, blk, 0, stream,
                           (const void*)cur, wpk_regh, reg_b, (const float*)nullptr,
                           slot + (size_t)3 * 512, gt + 3 * 256, bbt + 3 * 256, inv_cnt,
                           out_lvl, scales, l, H, W, 4, nTx, 32);
      }
    }
    out_lvl_off += (size_t)85 * HW;
    loc_off += HW;
  }
}

// Round 6
// 4867.179 us; speedup vs baseline: 1.4154x; 1.0156x over previous
//
#include <hip/hip_runtime.h>
#include <hip/hip_bf16.h>

#define TOT85 1722695ULL  // 85 * 20267

using short8 = __attribute__((ext_vector_type(8))) short;
using f32x4  = __attribute__((ext_vector_type(4))) float;

__device__ __forceinline__ float bfbits2f(short u) {
  return __uint_as_float(((unsigned int)(unsigned short)u) << 16);
}
__device__ __forceinline__ short f2bfbits(float f) {
  __hip_bfloat16 h = __float2bfloat16(f);
  return *reinterpret_cast<short*>(&h);
}

// repack conv weight [O][256][3][3] f32 -> [tap*8+chunk][NOCP oc][32 ic] bf16
// (weights consumed straight from global/L2; stride-32 rows = coalesced 1KB fragments)
__global__ __launch_bounds__(256) void repack_k(const float* __restrict__ src,
                                                __hip_bfloat16* __restrict__ dst,
                                                int O, int NOCP, int ocoff) {
  int idx = blockIdx.x * 256 + threadIdx.x;
  if (idx >= O * 2304) return;
  int o = idx / 2304;
  int r = idx - o * 2304;
  int i = r / 9;       // ic 0..255
  int t = r - i * 9;   // tap 0..8
  dst[((size_t)(t * 8 + (i >> 5)) * NOCP + (o + ocoff)) * 32 + (i & 31)] =
      __float2bfloat16(src[idx]);
}

__global__ void locations_k(float* __restrict__ out, int HW, int W, float s) {
  int i = blockIdx.x * 256 + threadIdx.x;
  if (i >= HW) return;
  int y = i / W, x = i - y * W;
  out[2 * i + 0] = x * s + 0.5f * s;
  out[2 * i + 1] = y * s + 0.5f * s;
}

// ---------------- tower kernel: 8M x 4N per wave, low arch-VGPR variant --------
// Block: 256 thr = 4 waves. Tile: 128 pixels (8 rows x 16 cols) x 256 ocs.
// Each wave owns a 64-oc slice (wave*64) and ALL 128 pixels: acc[8][4].
// B-operand (weights) VMEM stream per CU-tap is half of the 2Mx2N layout
// (no cross-wave duplication); A comes from LDS (parallel pipe).
// A-fragments are consumed in two halves of 4 (af[4] live, not af[8]) to keep
// arch VGPRs ~90 and avoid the r5 scratch spill (453 MB WRITE_SIZE pathology).
template <bool NORM_IN, bool SRC_NCHW>
__global__ __launch_bounds__(256, 2) void conv_tower_k(
    const void* __restrict__ srcv, const __hip_bfloat16* __restrict__ wpk,
    const float* __restrict__ bias, const float* __restrict__ statsIn,
    const float* __restrict__ gamma, const float* __restrict__ beta, float inv_cnt,
    __hip_bfloat16* __restrict__ dst, float* __restrict__ statsOut,
    int H, int W, int nTx) {
  __shared__ __align__(16) short s_in[180 * 40];
  __shared__ float s_red[64];
  __shared__ float s_a[256], s_c[256];

  const int tid = threadIdx.x;
  const int lane = tid & 63;
  const int wave = tid >> 6;  // 0..3 = oc-slice
  const int tIdx = blockIdx.x;
  const int ty = tIdx / nTx, tx = tIdx - ty * nTx;
  const int x0 = tx * 16, y0 = ty * 8;
  const int b = blockIdx.z;
  const int HW = H * W;
  const int l15 = lane & 15;
  const int kg = lane >> 4;  // 0..3
  const int q8 = (tid & 3) * 8;

  if (tid < 64) s_red[tid] = 0.f;
  if (NORM_IN) {
    int g = tid >> 3;
    float s = statsIn[(b * 32 + g) * 2 + 0];
    float ss = statsIn[(b * 32 + g) * 2 + 1];
    float m = s * inv_cnt;
    float var = fmaf(-m, m, ss * inv_cnt);
    float rs = rsqrtf(var + 1e-5f);
    float avv = rs * gamma[tid];
    s_a[tid] = avv;
    s_c[tid] = fmaf(-m, avv, beta[tid]);
  }

  f32x4 acc[8][4];
#pragma unroll
  for (int m = 0; m < 8; ++m)
#pragma unroll
    for (int n = 0; n < 4; ++n) acc[m][n] = (f32x4){0.f, 0.f, 0.f, 0.f};

  // per-lane weight pointer: elem = ((tap*8+chunk)*256 + wave*64 + n*16 + l15)*32 + kg*8
  const short* wlane = (const short*)wpk + ((wave * 64 + l15) * 32 + kg * 8);
  const size_t TAPSTR = (size_t)8 * 256 * 32;

  for (int chunk = 0; chunk < 8; ++chunk) {
    const int ic0 = chunk * 32;
    __syncthreads();  // protect s_in from previous chunk's readers (orders s_a/s_c too)
    if (SRC_NCHW) {
      const float* srcf = (const float*)srcv;
      const int pix = tid;
      if (pix < 180) {
        int prow = pix / 18;
        int pcol = pix - prow * 18;
        int gy = y0 + prow - 1, gx = x0 + pcol - 1;
        short8 sv[4];
        bool valid = (gy >= 0 && gy < H && gx >= 0 && gx < W);
        if (valid) {
          const float* p = srcf + (((size_t)(b * 256 + ic0)) * H + gy) * W + gx;
#pragma unroll
          for (int q = 0; q < 4; ++q)
#pragma unroll
            for (int j = 0; j < 8; ++j)
              sv[q][j] = f2bfbits(p[(size_t)(q * 8 + j) * HW]);
        } else {
#pragma unroll
          for (int q = 0; q < 4; ++q) sv[q] = (short8)0;
        }
#pragma unroll
        for (int q = 0; q < 4; ++q) *(short8*)(s_in + pix * 40 + q * 8) = sv[q];
      }
    } else {
      const __hip_bfloat16* srcb = (const __hip_bfloat16*)srcv;
      float av[8], cv[8];
#pragma unroll
      for (int j = 0; j < 8; ++j) {
        int c2 = ic0 + q8 + j;
        av[j] = s_a[c2];
        cv[j] = s_c[c2];
      }
      for (int idx = tid; idx < 720; idx += 256) {  // 180 pix x 4 quads(8ic)
        int pix = idx >> 2;
        int prow = pix / 18;
        int pcol = pix - prow * 18;
        int gy = y0 + prow - 1, gx = x0 + pcol - 1;
        short8 o8 = (short8)0;
        if (gy >= 0 && gy < H && gx >= 0 && gx < W) {
          const short* sp =
              (const short*)srcb + ((((size_t)b * H + gy) * W + gx) * 256 + ic0 + q8);
          short8 v8 = *(const short8*)sp;
#pragma unroll
          for (int j = 0; j < 8; ++j)
            o8[j] = f2bfbits(fmaxf(fmaf(bfbits2f(v8[j]), av[j], cv[j]), 0.f));
        }
        *(short8*)(s_in + pix * 40 + q8) = o8;
      }
    }
    __syncthreads();

    const short* wch = wlane + (size_t)chunk * 256 * 32;
    short8 bwA[4], bwB[4];
#pragma unroll
    for (int n = 0; n < 4; ++n) bwA[n] = *(const short8*)(wch + n * 512);

    auto tapbody = [&](int tap, short8 (&curw)[4], short8 (&nxtw)[4]) {
      if (tap < 8) {  // prefetch next tap's weights (L1/L2-resident)
        const short* wt = wch + (size_t)(tap + 1) * TAPSTR;
#pragma unroll
        for (int n = 0; n < 4; ++n) nxtw[n] = *(const short8*)(wt + n * 512);
      }
      const int dy = tap / 3, dx = tap - dy * 3;
      // per-tap base; A rows step by 18*40 shorts (compile-time immediates)
      const short* abase = s_in + ((dy * 18 + l15 + dx) * 40 + kg * 8);
#pragma unroll
      for (int mh = 0; mh < 2; ++mh) {  // two halves: af[4] live, not af[8]
        short8 af[4];
#pragma unroll
        for (int m = 0; m < 4; ++m)
          af[m] = *(const short8*)(abase + (mh * 4 + m) * (18 * 40));
#pragma unroll
        for (int m = 0; m < 4; ++m)
#pragma unroll
          for (int n = 0; n < 4; ++n)
            acc[mh * 4 + m][n] =
                __builtin_amdgcn_mfma_f32_16x16x32_bf16(af[m], curw[n], acc[mh * 4 + m][n],
                                                        0, 0, 0);
      }
    };
#pragma unroll
    for (int tap = 0; tap < 9; tap += 2) {
      tapbody(tap, bwA, bwB);
      if (tap + 1 < 9) tapbody(tap + 1, bwB, bwA);
    }
  }

  // epilogue: bias, NHWC bf16 store, GN stats
  const int masks[5] = {1, 2, 4, 16, 32};
#pragma unroll
  for (int n = 0; n < 4; ++n) {
    int oc_g = wave * 64 + n * 16 + l15;
    float bv = bias[oc_g];
    float lsum = 0.f, lssq = 0.f;
#pragma unroll
    for (int m = 0; m < 8; ++m) {
      int oy = y0 + m;
#pragma unroll
      for (int r = 0; r < 4; ++r) {
        int ox = x0 + kg * 4 + r;
        bool valid = (oy < H) && (ox < W);
        float v = acc[m][n][r] + bv;
        if (valid) {
          dst[(((size_t)b * H + oy) * W + ox) * 256 + oc_g] = __float2bfloat16(v);
          lsum += v;
          lssq += v * v;
        }
      }
    }
#pragma unroll
    for (int s = 0; s < 5; ++s) {
      lsum += __shfl_xor(lsum, masks[s], 64);
      lssq += __shfl_xor(lssq, masks[s], 64);
    }
    if ((lane & 55) == 0) {  // lanes 0 and 8: two 8-oc GN sub-groups
      int g2 = (wave * 8 + n * 2 + ((lane >> 3) & 1)) * 2;
      atomicAdd(&s_red[g2 + 0], lsum);
      atomicAdd(&s_red[g2 + 1], lssq);
    }
  }
  __syncthreads();
  if (tid < 64) atomicAdd(&statsOut[(size_t)b * 64 + tid], s_red[tid]);
}

// ---------------- head kernel (r1/r3 proven register path, 2Mx2N) ----------------
// OUT_MODE: 1 = d_out fp32 (logits oc<80, ctr oc==80 -> ch84);
//           2 = d_out fp32 expf(scale*v) at ch 80+oc.
template <int NREP, int OUT_MODE>
__global__ __launch_bounds__(256, 3) void conv_head_k(
    const void* __restrict__ srcv, const __hip_bfloat16* __restrict__ wpk,
    const float* __restrict__ bias, const float* __restrict__ bias2,
    const float* __restrict__ statsIn, const float* __restrict__ gamma,
    const float* __restrict__ beta, float inv_cnt,
    float* __restrict__ out, const float* __restrict__ scales, int lvl,
    int H, int W, int oc_valid, int nTx, int NOCP) {
  __shared__ __align__(16) short s_in[180 * 40];
  __shared__ float s_a[256], s_c[256];

  const int tid = threadIdx.x;
  const int lane = tid & 63;
  const int wave = tid >> 6;
  const int wm = wave >> 1;
  const int wn = wave & 1;
  const int tIdx = blockIdx.x;
  const int ty = tIdx / nTx, tx = tIdx - ty * nTx;
  const int x0 = tx * 16, y0 = ty * 8;
  const int b = blockIdx.z;
  const int HW = H * W;
  const int l15 = lane & 15;
  const int kg = lane >> 4;
  const int q8 = (tid & 3) * 8;

  {
    int g = tid >> 3;
    float s = statsIn[(b * 32 + g) * 2 + 0];
    float ss = statsIn[(b * 32 + g) * 2 + 1];
    float m = s * inv_cnt;
    float var = fmaf(-m, m, ss * inv_cnt);
    float rs = rsqrtf(var + 1e-5f);
    float avv = rs * gamma[tid];
    s_a[tid] = avv;
    s_c[tid] = fmaf(-m, avv, beta[tid]);
  }

  f32x4 acc[4][NREP];
#pragma unroll
  for (int m = 0; m < 4; ++m)
#pragma unroll
    for (int n = 0; n < NREP; ++n) acc[m][n] = (f32x4){0.f, 0.f, 0.f, 0.f};

  const short* wlane = (const short*)wpk + ((wn * NREP * 16 + l15) * 32 + kg * 8);
  const size_t TAPSTR = (size_t)8 * NOCP * 32;

  for (int chunk = 0; chunk < 8; ++chunk) {
    const int ic0 = chunk * 32;
    __syncthreads();
    {
      const __hip_bfloat16* srcb = (const __hip_bfloat16*)srcv;
      float av[8], cv[8];
#pragma unroll
      for (int j = 0; j < 8; ++j) {
        int c2 = ic0 + q8 + j;
        av[j] = s_a[c2];
        cv[j] = s_c[c2];
      }
      for (int idx = tid; idx < 720; idx += 256) {
        int pix = idx >> 2;
        int prow = pix / 18;
        int pcol = pix - prow * 18;
        int gy = y0 + prow - 1, gx = x0 + pcol - 1;
        short8 o8 = (short8)0;
        if (gy >= 0 && gy < H && gx >= 0 && gx < W) {
          const short* sp =
              (const short*)srcb + ((((size_t)b * H + gy) * W + gx) * 256 + ic0 + q8);
          short8 v8 = *(const short8*)sp;
#pragma unroll
          for (int j = 0; j < 8; ++j)
            o8[j] = f2bfbits(fmaxf(fmaf(bfbits2f(v8[j]), av[j], cv[j]), 0.f));
        }
        *(short8*)(s_in + pix * 40 + q8) = o8;
      }
    }
    __syncthreads();

    const short* wch = wlane + (size_t)chunk * NOCP * 32;
    short8 bwA[NREP], bwB[NREP];
#pragma unroll
    for (int n = 0; n < NREP; ++n) bwA[n] = *(const short8*)(wch + n * 512);

    auto tapbody = [&](int tap, short8 (&curw)[NREP], short8 (&nxtw)[NREP]) {
      if (tap < 8) {
        const short* wt = wch + (size_t)(tap + 1) * TAPSTR;
#pragma unroll
        for (int n = 0; n < NREP; ++n) nxtw[n] = *(const short8*)(wt + n * 512);
      }
      const int dy = tap / 3, dx = tap - dy * 3;
      short8 af[4];
#pragma unroll
      for (int m = 0; m < 4; ++m)
        af[m] = *(const short8*)(s_in + ((wm * 4 + m + dy) * 18 + (l15 + dx)) * 40 + kg * 8);
#pragma unroll
      for (int m = 0; m < 4; ++m)
#pragma unroll
        for (int n = 0; n < NREP; ++n)
          acc[m][n] = __builtin_amdgcn_mfma_f32_16x16x32_bf16(af[m], curw[n], acc[m][n], 0, 0, 0);
    };
#pragma unroll
    for (int tap = 0; tap < 9; tap += 2) {
      tapbody(tap, bwA, bwB);
      if (tap + 1 < 9) tapbody(tap + 1, bwB, bwA);
    }
  }

#pragma unroll
  for (int n = 0; n < NREP; ++n) {
    int oc_l = wn * NREP * 16 + n * 16 + l15;
    float bv;
    if (OUT_MODE == 1)
      bv = (oc_l < 80) ? bias[oc_l] : ((oc_l == 80) ? bias2[0] : 0.f);
    else
      bv = (oc_l < oc_valid) ? bias[oc_l] : 0.f;
#pragma unroll
    for (int m = 0; m < 4; ++m) {
      int oy = y0 + wm * 4 + m;
#pragma unroll
      for (int r = 0; r < 4; ++r) {
        int ox = x0 + kg * 4 + r;
        bool valid = (oy < H) && (ox < W) && (oc_l < oc_valid);
        float v = acc[m][n][r] + bv;
        if (valid) {
          if (OUT_MODE == 1) {
            int och = (oc_l == 80) ? 84 : oc_l;
            out[(size_t)b * TOT85 + (size_t)och * HW + oy * W + ox] = v;
          } else {
            out[(size_t)b * TOT85 + (size_t)(80 + oc_l) * HW + oy * W + ox] =
                expf(scales[lvl] * v);
          }
        }
      }
    }
  }
}

extern "C" void kernel_launch(void* const* d_in, const int* in_sizes, int n_in,
                              void* d_out_v, int out_size, void* d_ws, size_t ws_size,
                              hipStream_t stream) {
  (void)in_sizes; (void)n_in; (void)out_size; (void)ws_size;
  static const int HS[5] = {100, 50, 25, 13, 7};
  static const int WSd[5] = {152, 76, 38, 19, 10};
  static const int STRD[5] = {8, 16, 32, 64, 128};

  const float* feat[5];
  for (int i = 0; i < 5; ++i) feat[i] = (const float*)d_in[i];
  const float* cls_w = (const float*)d_in[5];
  const float* cls_b = (const float*)d_in[6];
  const float* cls_g = (const float*)d_in[7];
  const float* cls_bb = (const float*)d_in[8];
  const float* box_w = (const float*)d_in[9];
  const float* box_b = (const float*)d_in[10];
  const float* box_g = (const float*)d_in[11];
  const float* box_bb = (const float*)d_in[12];
  const float* logits_w = (const float*)d_in[13];
  const float* logits_b = (const float*)d_in[14];
  const float* ctr_w = (const float*)d_in[15];
  const float* ctr_b = (const float*)d_in[16];
  const float* reg_w = (const float*)d_in[17];
  const float* reg_b = (const float*)d_in[18];
  const float* scales = (const float*)d_in[19];
  float* d_out = (float*)d_out_v;

  char* wsp = (char*)d_ws;
  size_t off = 0;
  auto carve = [&](size_t bytes) -> char* {
    char* p = wsp + off;
    off += (bytes + 255) & ~(size_t)255;
    return p;
  };
  const size_t MAXE = (size_t)8 * 100 * 152 * 256;  // 31.13M elems
  __hip_bfloat16* bufA = (__hip_bfloat16*)carve(MAXE * 2);
  __hip_bfloat16* bufB = (__hip_bfloat16*)carve(MAXE * 2);
  const size_t TW = (size_t)9 * 8 * 256 * 32;  // per tower conv
  __hip_bfloat16* wpk_cls = (__hip_bfloat16*)carve(4 * TW * 2);
  __hip_bfloat16* wpk_box = (__hip_bfloat16*)carve(4 * TW * 2);
  __hip_bfloat16* wpk_clsh = (__hip_bfloat16*)carve((size_t)9 * 8 * 96 * 32 * 2);
  __hip_bfloat16* wpk_regh = (__hip_bfloat16*)carve((size_t)9 * 8 * 32 * 32 * 2);
  float* stats_all = (float*)carve((size_t)40 * 8 * 64 * 4);

  hipMemsetAsync(stats_all, 0, (size_t)40 * 8 * 64 * 4, stream);

  auto rp = [&](const float* s, __hip_bfloat16* d, int O, int NOCP, int ocoff) {
    int total = O * 2304;
    hipLaunchKernelGGL(repack_k, dim3((total + 255) / 256), dim3(256), 0, stream, s, d, O, NOCP,
                       ocoff);
  };
  for (int i = 0; i < 4; ++i) {
    rp(cls_w + (size_t)i * 256 * 2304, wpk_cls + (size_t)i * TW, 256, 256, 0);
    rp(box_w + (size_t)i * 256 * 2304, wpk_box + (size_t)i * TW, 256, 256, 0);
  }
  rp(logits_w, wpk_clsh, 80, 96, 0);
  rp(ctr_w, wpk_clsh, 1, 96, 80);
  rp(reg_w, wpk_regh, 4, 32, 0);

  size_t out_lvl_off = 0, loc_off = 0;
  const size_t OUT0 = (size_t)8 * TOT85;

  for (int l = 0; l < 5; ++l) {
    int H = HS[l], W = WSd[l], HW = H * W;
    int nTx = (W + 15) / 16, nTy = (H + 7) / 8;
    dim3 grid(nTx * nTy, 1, 8);
    dim3 blk(256);
    float inv_cnt = 1.f / (8.f * (float)HW);
    float* out_lvl = d_out + out_lvl_off;

    hipLaunchKernelGGL(locations_k, dim3((HW + 255) / 256), blk, 0, stream,
                       d_out + OUT0 + 2 * loc_off, HW, W, (float)STRD[l]);

    for (int t = 0; t < 2; ++t) {
      const __hip_bfloat16* wpkT = (t == 0) ? wpk_cls : wpk_box;
      const float* bt = (t == 0) ? cls_b : box_b;
      const float* gt = (t == 0) ? cls_g : box_g;
      const float* bbt = (t == 0) ? cls_bb : box_bb;
      float* slot = stats_all + (size_t)(l * 2 + t) * 4 * 512;  // 512 floats per conv slot

      // conv 0: NCHW f32 input, no norm, writes stats slot 0
      hipLaunchKernelGGL((conv_tower_k<false, true>), grid, blk, 0, stream,
                         (const void*)feat[l], wpkT, bt, (const float*)nullptr,
                         (const float*)nullptr, (const float*)nullptr, 0.f, bufA, slot, H, W,
                         nTx);
      __hip_bfloat16* cur = bufA;
      __hip_bfloat16* nxt = bufB;
      for (int i = 1; i < 4; ++i) {
        hipLaunchKernelGGL((conv_tower_k<true, false>), grid, blk, 0, stream,
                           (const void*)cur, wpkT + (size_t)i * TW, bt + i * 256,
                           slot + (size_t)(i - 1) * 512, gt + (i - 1) * 256,
                           bbt + (i - 1) * 256, inv_cnt, nxt, slot + (size_t)i * 512, H, W,
                           nTx);
        __hip_bfloat16* tmp = cur;
        cur = nxt;
        nxt = tmp;
      }
      if (t == 0) {
        hipLaunchKernelGGL((conv_head_k<3, 1>), grid, blk, 0, stream,
                           (const void*)cur, wpk_clsh, logits_b, ctr_b,
                           slot + (size_t)3 * 512, gt + 3 * 256, bbt + 3 * 256, inv_cnt,
                           out_lvl, scales, l, H, W, 81, nTx, 96);
      } else {
        hipLaunchKernelGGL((conv_head_k<1, 2>), grid, blk, 0, stream,
                           (const void*)cur, wpk_regh, reg_b, (const float*)nullptr,
                           slot + (size_t)3 * 512, gt + 3 * 256, bbt + 3 * 256, inv_cnt,
                           out_lvl, scales, l, H, W, 4, nTx, 32);
      }
    }
    out_lvl_off += (size_t)85 * HW;
    loc_off += HW;
  }
}